// Round 1
// baseline (405.300 us; speedup 1.0000x reference)
//
#include <hip/hip_runtime.h>

// SpikingSiameseNetwork forward, MI355X/gfx950.
// Pipeline: prep(weight 3-way bf16 split) -> GEMM1(all t) -> LIF1 scan ->
//           GEMM2(all t) -> LIF2 scan -> normalize+mean epilogue.
// Numerics: activations are exactly {0,1} (exact in bf16); weights split into
// 3 bf16 parts summed in the fp32 MFMA accumulator => ~fp32-GEMM-exact.

typedef short bf16x8 __attribute__((ext_vector_type(8)));
typedef float f32x4 __attribute__((ext_vector_type(4)));

#define RBIG 51200  // BS(2048) * T(25)

// ---------------- prep: split fp32 weights into 3 bf16 parts --------------
// W1s layout: [path][256][s*512 + k]  (n-major rows of length 1536)
// W2s layout: [path][128][s*256 + k]  (rows of length 768)
__global__ void prep_w(const float* __restrict__ Wa1, const float* __restrict__ Wv1,
                       const float* __restrict__ Wa2, const float* __restrict__ Wv2,
                       unsigned short* __restrict__ W1s, unsigned short* __restrict__ W2s) {
    int idx = blockIdx.x * 256 + threadIdx.x;  // total 327680 exactly
    float w;
    unsigned short* dst;
    int K, k;
    if (idx < 262144) {
        int p = idx >> 17, rem = idx & 131071;
        int n = rem >> 9; k = rem & 511; K = 512;
        const float* src = p ? Wv1 : Wa1;
        w = src[(size_t)n * 512 + k];
        dst = W1s + (size_t)p * 256 * 1536 + (size_t)n * 1536;
    } else {
        int j = idx - 262144;
        int p = j >> 15, rem = j & 32767;
        int n = rem >> 8; k = rem & 255; K = 256;
        const float* src = p ? Wv2 : Wa2;
        w = src[(size_t)n * 256 + k];
        dst = W2s + (size_t)p * 128 * 768 + (size_t)n * 768;
    }
    // exact splits: hi = trunc16(w); mid = trunc16(w-hi); lo = trunc16(residual)
    unsigned int u  = __float_as_uint(w);
    unsigned int hi = u & 0xFFFF0000u;
    float r1 = w - __uint_as_float(hi);         // exact
    unsigned int mi = __float_as_uint(r1) & 0xFFFF0000u;
    float r2 = r1 - __uint_as_float(mi);        // exact
    dst[k]         = (unsigned short)(hi >> 16);
    dst[K + k]     = (unsigned short)(mi >> 16);
    dst[2 * K + k] = (unsigned short)(__float_as_uint(r2) >> 16);
}

// ---------------- GEMM: C[51200 x NT] = A[51200 x KSRC] * W'^T -------------
// 128x128 block tile, BK=64, 4 waves (64x64 each), 16x16x32 bf16 MFMA.
// K_eff = 3*KSRC (3 splits); A-chunk staged once per kb, reused for s=0..2.
template <int KSRC, int NT, bool AF32>
__global__ __launch_bounds__(256, 2) void gemm_spl(
    const void* __restrict__ A0, const void* __restrict__ A1,
    const unsigned short* __restrict__ Ws, float* __restrict__ C) {
    constexpr int KE  = 3 * KSRC;
    constexpr int NKB = KSRC / 64;
    constexpr int NC  = 3 * NKB;

    __shared__ unsigned short As[2][128 * 64];  // 32 KB
    __shared__ unsigned short Bs[2][128 * 64];  // 32 KB

    const int tid  = threadIdx.x;
    const int bx   = blockIdx.x, by = blockIdx.y, bz = blockIdx.z;
    const int lane = tid & 63, wave = tid >> 6;
    const int wm   = wave >> 1, wn = wave & 1;
    const size_t row0 = (size_t)bx * 128;
    const unsigned short* Wp = Ws + (size_t)bz * NT * KE + (size_t)by * 128 * KE;

    f32x4 acc[4][4];
    f32x4 zz = {0.f, 0.f, 0.f, 0.f};
#pragma unroll
    for (int i = 0; i < 4; ++i)
#pragma unroll
        for (int j = 0; j < 4; ++j) acc[i][j] = zz;

    auto stageA = [&](int buf, int kb) {
        if constexpr (AF32) {
            const float* Ag = (const float*)(bz ? A1 : A0);
#pragma unroll
            for (int j = 0; j < 8; ++j) {
                int lin = tid + (j << 8);       // 0..2047 float4 slots
                int row = lin >> 4, f4 = lin & 15;
                float4 v = *(const float4*)(Ag + (row0 + row) * KSRC + kb * 64 + (f4 << 2));
                // values are exactly 0.0f/1.0f -> bf16 truncation exact
                uint2 pk;
                pk.x = (__float_as_uint(v.y) & 0xFFFF0000u) | (__float_as_uint(v.x) >> 16);
                pk.y = (__float_as_uint(v.w) & 0xFFFF0000u) | (__float_as_uint(v.z) >> 16);
                *(uint2*)&As[buf][row * 64 + (f4 << 2)] = pk;
            }
        } else {
            const unsigned short* Ag = (const unsigned short*)(bz ? A1 : A0);
#pragma unroll
            for (int j = 0; j < 4; ++j) {
                int slot = (tid << 3) + (j << 11);
                int row = slot >> 6, col = slot & 63;
                uint4 v = *(const uint4*)(Ag + (row0 + row) * KSRC + kb * 64 + col);
                *(uint4*)&As[buf][slot] = v;
            }
        }
    };
    auto stageB = [&](int buf, int kb, int s) {
        const unsigned short* Bg = Wp + (size_t)s * KSRC + kb * 64;
#pragma unroll
        for (int j = 0; j < 4; ++j) {
            int slot = (tid << 3) + (j << 11);
            int row = slot >> 6, col = slot & 63;
            uint4 v = *(const uint4*)(Bg + (size_t)row * KE + col);
            *(uint4*)&Bs[buf][slot] = v;
        }
    };

    stageA(0, 0);
    stageB(0, 0, 0);
    int kb = 0, s = 0;
    for (int c = 0; c < NC; ++c) {
        __syncthreads();  // staged data for chunk c visible; prior readers done
        int s1 = s + 1, kb1 = kb;
        if (s1 == 3) { s1 = 0; kb1 = kb + 1; }
        if (c + 1 < NC) {
            stageB((c + 1) & 1, kb1, s1);
            if (s1 == 0) stageA(kb1 & 1, kb1);
        }
        const unsigned short* Ab = As[kb & 1];
        const unsigned short* Bb = Bs[c & 1];
#pragma unroll
        for (int ks = 0; ks < 2; ++ks) {
            int ko = ks * 32 + ((lane >> 4) << 3);
            bf16x8 af[4], bb[4];
#pragma unroll
            for (int mi2 = 0; mi2 < 4; ++mi2)
                af[mi2] = *(const bf16x8*)&Ab[(wm * 64 + mi2 * 16 + (lane & 15)) * 64 + ko];
#pragma unroll
            for (int ni = 0; ni < 4; ++ni)
                bb[ni] = *(const bf16x8*)&Bb[(wn * 64 + ni * 16 + (lane & 15)) * 64 + ko];
#pragma unroll
            for (int mi2 = 0; mi2 < 4; ++mi2)
#pragma unroll
                for (int ni = 0; ni < 4; ++ni)
                    acc[mi2][ni] = __builtin_amdgcn_mfma_f32_16x16x32_bf16(
                        af[mi2], bb[ni], acc[mi2][ni], 0, 0, 0);
        }
        kb = kb1; s = s1;
    }

    // epilogue: C/D layout col=lane&15, row=(lane>>4)*4+reg (m89-verified)
    float* Cp = C + (size_t)bz * RBIG * NT;
    int r4 = ((lane >> 4) << 2), cl = lane & 15;
#pragma unroll
    for (int mi2 = 0; mi2 < 4; ++mi2)
#pragma unroll
        for (int ni = 0; ni < 4; ++ni) {
            size_t col = (size_t)by * 128 + wn * 64 + ni * 16 + cl;
#pragma unroll
            for (int j = 0; j < 4; ++j) {
                size_t row = row0 + wm * 64 + mi2 * 16 + r4 + j;
                Cp[row * NT + col] = acc[mi2][ni][j];
            }
        }
}

// ---------------- LIF layer 1: scan over t, emit bf16 spikes ---------------
// cur layout [p][rho][256]; spikes packed 2/bf16 per u32. thread d -> h=2d,2d+1
__global__ void lif1_k(const float* __restrict__ cur, const float* __restrict__ ba1,
                       const float* __restrict__ bv1, unsigned int* __restrict__ spk) {
    int r = blockIdx.x, p = blockIdx.y, d = threadIdx.x;  // 128 threads
    const float* c0 = cur + ((size_t)p * RBIG + (size_t)r * 25) * 256 + 2 * d;
    const float* bias = p ? bv1 : ba1;
    float b0 = bias[2 * d], b1 = bias[2 * d + 1];
    float2 cv[25];
#pragma unroll
    for (int t = 0; t < 25; ++t) cv[t] = *(const float2*)(c0 + (size_t)t * 256);
    unsigned int* sp = spk + ((size_t)p * RBIG + (size_t)r * 25) * 128 + d;
    float m0 = 0.f, m1 = 0.f;
#pragma unroll
    for (int t = 0; t < 25; ++t) {
        float r0 = (m0 > 1.f) ? 1.f : 0.f;  // reset from PREVIOUS mem
        float r1 = (m1 > 1.f) ? 1.f : 0.f;
        m0 = 0.9f * m0 + (cv[t].x + b0) - r0;
        m1 = 0.9f * m1 + (cv[t].y + b1) - r1;
        unsigned int w = (m0 > 1.f ? 0x3F80u : 0u) | (m1 > 1.f ? 0x3F800000u : 0u);
        sp[(size_t)t * 128] = w;
    }
}

// ---------------- LIF layer 2: scan over t, keep only t=24 spikes ----------
__global__ void lif2_k(const float* __restrict__ cur2, const float* __restrict__ ba2,
                       const float* __restrict__ bv2, float* __restrict__ spk2) {
    int r = blockIdx.x, p = blockIdx.y, d = threadIdx.x;  // 64 threads
    const float* c0 = cur2 + ((size_t)p * RBIG + (size_t)r * 25) * 128 + 2 * d;
    const float* bias = p ? bv2 : ba2;
    float b0 = bias[2 * d], b1 = bias[2 * d + 1];
    float2 cv[25];
#pragma unroll
    for (int t = 0; t < 25; ++t) cv[t] = *(const float2*)(c0 + (size_t)t * 128);
    float m0 = 0.f, m1 = 0.f;
#pragma unroll
    for (int t = 0; t < 25; ++t) {
        float r0 = (m0 > 1.f) ? 1.f : 0.f;
        float r1 = (m1 > 1.f) ? 1.f : 0.f;
        m0 = 0.9f * m0 + (cv[t].x + b0) - r0;
        m1 = 0.9f * m1 + (cv[t].y + b1) - r1;
    }
    float2 o;
    o.x = (m0 > 1.f) ? 1.f : 0.f;
    o.y = (m1 > 1.f) ? 1.f : 0.f;
    *(float2*)(spk2 + ((size_t)p * 2048 + r) * 128 + 2 * d) = o;
}

// ---------------- epilogue: concat -> L2 normalize -> mean over S ----------
__global__ void epi_k(const float* __restrict__ spk2, float* __restrict__ out) {
    int b = blockIdx.x, d = threadIdx.x;  // 256 threads, d = output dim
    int p = d >> 7, e = d & 127;
    __shared__ float red[256];
    float acc = 0.f;
    for (int s = 0; s < 8; ++s) {
        float v = spk2[((size_t)p * 2048 + (size_t)(b * 8 + s)) * 128 + e];
        red[d] = v * v;
        __syncthreads();
        for (int off = 128; off > 0; off >>= 1) {
            if (d < off) red[d] += red[d + off];
            __syncthreads();
        }
        float nrm = sqrtf(red[0]);
        acc += v / fmaxf(nrm, 1e-12f);
        __syncthreads();  // protect red before next s
    }
    out[(size_t)b * 256 + d] = acc * 0.125f;
}

extern "C" void kernel_launch(void* const* d_in, const int* in_sizes, int n_in,
                              void* d_out, int out_size, void* d_ws, size_t ws_size,
                              hipStream_t stream) {
    const float* a_seq = (const float*)d_in[0];
    const float* v_seq = (const float*)d_in[1];
    const float* W_a1  = (const float*)d_in[2];
    const float* b_a1  = (const float*)d_in[3];
    const float* W_a2  = (const float*)d_in[4];
    const float* b_a2  = (const float*)d_in[5];
    const float* W_v1  = (const float*)d_in[6];
    const float* b_v1  = (const float*)d_in[7];
    const float* W_v2  = (const float*)d_in[8];
    const float* b_v2  = (const float*)d_in[9];

    // workspace layout (needs ~161.4 MB)
    char* ws = (char*)d_ws;
    unsigned short* W1s  = (unsigned short*)(ws);              // 1,572,864 B
    unsigned short* W2s  = (unsigned short*)(ws + 1572864);    //   393,216 B
    unsigned short* spk1 = (unsigned short*)(ws + 1966080);    // 52,428,800 B
    float*          curb = (float*)(ws + 54394880);            // 104,857,600 B (cur1; reused as cur2)
    float*          spk2 = (float*)(ws + 159252480);           // 2,097,152 B
    float*          out  = (float*)d_out;

    prep_w<<<1280, 256, 0, stream>>>(W_a1, W_v1, W_a2, W_v2, W1s, W2s);

    // layer 1: cur1[p][51200][256]
    gemm_spl<512, 256, true><<<dim3(400, 2, 2), 256, 0, stream>>>(a_seq, v_seq, W1s, curb);
    lif1_k<<<dim3(2048, 2), 128, 0, stream>>>(curb, b_a1, b_v1, (unsigned int*)spk1);

    // layer 2: cur2[p][51200][128] (reuses curb)
    gemm_spl<256, 128, false><<<dim3(400, 1, 2), 256, 0, stream>>>(
        spk1, spk1 + (size_t)RBIG * 256, W2s, curb);
    lif2_k<<<dim3(2048, 2), 64, 0, stream>>>(curb, b_a2, b_v2, spk2);

    epi_k<<<256, 256, 0, stream>>>(spk2, out);
}

// Round 2
// 377.247 us; speedup vs baseline: 1.0744x; 1.0744x over previous
//
#include <hip/hip_runtime.h>

// SpikingSiameseNetwork forward, MI355X/gfx950.
// Pipeline: prep(weight 3-way bf16 split) -> GEMM1(all t) -> LIF1 scan ->
//           GEMM2(all t) -> LIF2 scan -> normalize+mean epilogue.
// Numerics: activations are exactly {0,1} (exact in bf16); weights split into
// 3 bf16 parts summed in the fp32 MFMA accumulator => ~fp32-GEMM-exact.
// R2: T2 XOR-swizzle on LDS tiles (R1 counters: bank-conflict stalls = 28%
// of GEMM cycles, 16-way conflict on 128B-stride fragment reads).

typedef short bf16x8 __attribute__((ext_vector_type(8)));
typedef float f32x4 __attribute__((ext_vector_type(4)));

#define RBIG 51200  // BS(2048) * T(25)

// ---------------- prep: split fp32 weights into 3 bf16 parts --------------
// W1s layout: [path][256][s*512 + k]  (n-major rows of length 1536)
// W2s layout: [path][128][s*256 + k]  (rows of length 768)
__global__ void prep_w(const float* __restrict__ Wa1, const float* __restrict__ Wv1,
                       const float* __restrict__ Wa2, const float* __restrict__ Wv2,
                       unsigned short* __restrict__ W1s, unsigned short* __restrict__ W2s) {
    int idx = blockIdx.x * 256 + threadIdx.x;  // total 327680 exactly
    float w;
    unsigned short* dst;
    int K, k;
    if (idx < 262144) {
        int p = idx >> 17, rem = idx & 131071;
        int n = rem >> 9; k = rem & 511; K = 512;
        const float* src = p ? Wv1 : Wa1;
        w = src[(size_t)n * 512 + k];
        dst = W1s + (size_t)p * 256 * 1536 + (size_t)n * 1536;
    } else {
        int j = idx - 262144;
        int p = j >> 15, rem = j & 32767;
        int n = rem >> 8; k = rem & 255; K = 256;
        const float* src = p ? Wv2 : Wa2;
        w = src[(size_t)n * 256 + k];
        dst = W2s + (size_t)p * 128 * 768 + (size_t)n * 768;
    }
    // exact splits: hi = trunc16(w); mid = trunc16(w-hi); lo = trunc16(residual)
    unsigned int u  = __float_as_uint(w);
    unsigned int hi = u & 0xFFFF0000u;
    float r1 = w - __uint_as_float(hi);         // exact
    unsigned int mi = __float_as_uint(r1) & 0xFFFF0000u;
    float r2 = r1 - __uint_as_float(mi);        // exact
    dst[k]         = (unsigned short)(hi >> 16);
    dst[K + k]     = (unsigned short)(mi >> 16);
    dst[2 * K + k] = (unsigned short)(__float_as_uint(r2) >> 16);
}

// ---------------- GEMM: C[51200 x NT] = A[51200 x KSRC] * W'^T -------------
// 128x128 block tile, BK=64, 4 waves (64x64 each), 16x16x32 bf16 MFMA.
// K_eff = 3*KSRC (3 splits); A-chunk staged once per kb, reused for s=0..2.
// LDS tiles XOR-swizzled: elem ^= ((row&7)<<3)  (byte ^= (row&7)<<4) so the
// 16-lane consecutive-row fragment read spreads over 8 distinct 16B slots.
template <int KSRC, int NT, bool AF32>
__global__ __launch_bounds__(256, 2) void gemm_spl(
    const void* __restrict__ A0, const void* __restrict__ A1,
    const unsigned short* __restrict__ Ws, float* __restrict__ C) {
    constexpr int KE  = 3 * KSRC;
    constexpr int NKB = KSRC / 64;
    constexpr int NC  = 3 * NKB;

    __shared__ unsigned short As[2][128 * 64];  // 32 KB
    __shared__ unsigned short Bs[2][128 * 64];  // 32 KB

    const int tid  = threadIdx.x;
    const int bx   = blockIdx.x, by = blockIdx.y, bz = blockIdx.z;
    const int lane = tid & 63, wave = tid >> 6;
    const int wm   = wave >> 1, wn = wave & 1;
    const size_t row0 = (size_t)bx * 128;
    const unsigned short* Wp = Ws + (size_t)bz * NT * KE + (size_t)by * 128 * KE;

    f32x4 acc[4][4];
    f32x4 zz = {0.f, 0.f, 0.f, 0.f};
#pragma unroll
    for (int i = 0; i < 4; ++i)
#pragma unroll
        for (int j = 0; j < 4; ++j) acc[i][j] = zz;

    auto stageA = [&](int buf, int kb) {
        if constexpr (AF32) {
            const float* Ag = (const float*)(bz ? A1 : A0);
#pragma unroll
            for (int j = 0; j < 8; ++j) {
                int lin = tid + (j << 8);       // 0..2047 float4 slots
                int row = lin >> 4, f4 = lin & 15;
                float4 v = *(const float4*)(Ag + (row0 + row) * KSRC + kb * 64 + (f4 << 2));
                // values are exactly 0.0f/1.0f -> bf16 truncation exact
                uint2 pk;
                pk.x = (__float_as_uint(v.y) & 0xFFFF0000u) | (__float_as_uint(v.x) >> 16);
                pk.y = (__float_as_uint(v.w) & 0xFFFF0000u) | (__float_as_uint(v.z) >> 16);
                int idx = (row * 64 + (f4 << 2)) ^ ((row & 7) << 3);
                *(uint2*)&As[buf][idx] = pk;
            }
        } else {
            const unsigned short* Ag = (const unsigned short*)(bz ? A1 : A0);
#pragma unroll
            for (int j = 0; j < 4; ++j) {
                int slot = (tid << 3) + (j << 11);
                int row = slot >> 6, col = slot & 63;
                uint4 v = *(const uint4*)(Ag + (row0 + row) * KSRC + kb * 64 + col);
                int idx = slot ^ ((row & 7) << 3);
                *(uint4*)&As[buf][idx] = v;
            }
        }
    };
    auto stageB = [&](int buf, int kb, int s) {
        const unsigned short* Bg = Wp + (size_t)s * KSRC + kb * 64;
#pragma unroll
        for (int j = 0; j < 4; ++j) {
            int slot = (tid << 3) + (j << 11);
            int row = slot >> 6, col = slot & 63;
            uint4 v = *(const uint4*)(Bg + (size_t)row * KE + col);
            int idx = slot ^ ((row & 7) << 3);
            *(uint4*)&Bs[buf][idx] = v;
        }
    };

    stageA(0, 0);
    stageB(0, 0, 0);
    int kb = 0, s = 0;
    const int swz = (lane & 7) << 3;  // row&7 == lane&7 for fragment rows
    for (int c = 0; c < NC; ++c) {
        __syncthreads();  // staged data for chunk c visible; prior readers done
        int s1 = s + 1, kb1 = kb;
        if (s1 == 3) { s1 = 0; kb1 = kb + 1; }
        if (c + 1 < NC) {
            stageB((c + 1) & 1, kb1, s1);
            if (s1 == 0) stageA(kb1 & 1, kb1);
        }
        const unsigned short* Ab = As[kb & 1];
        const unsigned short* Bb = Bs[c & 1];
#pragma unroll
        for (int ks = 0; ks < 2; ++ks) {
            int ko = ks * 32 + ((lane >> 4) << 3);
            bf16x8 af[4], bb[4];
#pragma unroll
            for (int mi2 = 0; mi2 < 4; ++mi2) {
                int Rm = wm * 64 + mi2 * 16 + (lane & 15);
                af[mi2] = *(const bf16x8*)&Ab[(Rm * 64 + ko) ^ swz];
            }
#pragma unroll
            for (int ni = 0; ni < 4; ++ni) {
                int Rn = wn * 64 + ni * 16 + (lane & 15);
                bb[ni] = *(const bf16x8*)&Bb[(Rn * 64 + ko) ^ swz];
            }
#pragma unroll
            for (int mi2 = 0; mi2 < 4; ++mi2)
#pragma unroll
                for (int ni = 0; ni < 4; ++ni)
                    acc[mi2][ni] = __builtin_amdgcn_mfma_f32_16x16x32_bf16(
                        af[mi2], bb[ni], acc[mi2][ni], 0, 0, 0);
        }
        kb = kb1; s = s1;
    }

    // epilogue: C/D layout col=lane&15, row=(lane>>4)*4+reg (m89-verified)
    float* Cp = C + (size_t)bz * RBIG * NT;
    int r4 = ((lane >> 4) << 2), cl = lane & 15;
#pragma unroll
    for (int mi2 = 0; mi2 < 4; ++mi2)
#pragma unroll
        for (int ni = 0; ni < 4; ++ni) {
            size_t col = (size_t)by * 128 + wn * 64 + ni * 16 + cl;
#pragma unroll
            for (int j = 0; j < 4; ++j) {
                size_t row = row0 + wm * 64 + mi2 * 16 + r4 + j;
                Cp[row * NT + col] = acc[mi2][ni][j];
            }
        }
}

// ---------------- LIF layer 1: scan over t, emit bf16 spikes ---------------
// cur layout [p][rho][256]; spikes packed 2/bf16 per u32. thread d -> h=2d,2d+1
__global__ void lif1_k(const float* __restrict__ cur, const float* __restrict__ ba1,
                       const float* __restrict__ bv1, unsigned int* __restrict__ spk) {
    int r = blockIdx.x, p = blockIdx.y, d = threadIdx.x;  // 128 threads
    const float* c0 = cur + ((size_t)p * RBIG + (size_t)r * 25) * 256 + 2 * d;
    const float* bias = p ? bv1 : ba1;
    float b0 = bias[2 * d], b1 = bias[2 * d + 1];
    float2 cv[25];
#pragma unroll
    for (int t = 0; t < 25; ++t) cv[t] = *(const float2*)(c0 + (size_t)t * 256);
    unsigned int* sp = spk + ((size_t)p * RBIG + (size_t)r * 25) * 128 + d;
    float m0 = 0.f, m1 = 0.f;
#pragma unroll
    for (int t = 0; t < 25; ++t) {
        float r0 = (m0 > 1.f) ? 1.f : 0.f;  // reset from PREVIOUS mem
        float r1 = (m1 > 1.f) ? 1.f : 0.f;
        m0 = 0.9f * m0 + (cv[t].x + b0) - r0;
        m1 = 0.9f * m1 + (cv[t].y + b1) - r1;
        unsigned int w = (m0 > 1.f ? 0x3F80u : 0u) | (m1 > 1.f ? 0x3F800000u : 0u);
        sp[(size_t)t * 128] = w;
    }
}

// ---------------- LIF layer 2: scan over t, keep only t=24 spikes ----------
__global__ void lif2_k(const float* __restrict__ cur2, const float* __restrict__ ba2,
                       const float* __restrict__ bv2, float* __restrict__ spk2) {
    int r = blockIdx.x, p = blockIdx.y, d = threadIdx.x;  // 64 threads
    const float* c0 = cur2 + ((size_t)p * RBIG + (size_t)r * 25) * 128 + 2 * d;
    const float* bias = p ? bv2 : ba2;
    float b0 = bias[2 * d], b1 = bias[2 * d + 1];
    float2 cv[25];
#pragma unroll
    for (int t = 0; t < 25; ++t) cv[t] = *(const float2*)(c0 + (size_t)t * 128);
    float m0 = 0.f, m1 = 0.f;
#pragma unroll
    for (int t = 0; t < 25; ++t) {
        float r0 = (m0 > 1.f) ? 1.f : 0.f;
        float r1 = (m1 > 1.f) ? 1.f : 0.f;
        m0 = 0.9f * m0 + (cv[t].x + b0) - r0;
        m1 = 0.9f * m1 + (cv[t].y + b1) - r1;
    }
    float2 o;
    o.x = (m0 > 1.f) ? 1.f : 0.f;
    o.y = (m1 > 1.f) ? 1.f : 0.f;
    *(float2*)(spk2 + ((size_t)p * 2048 + r) * 128 + 2 * d) = o;
}

// ---------------- epilogue: concat -> L2 normalize -> mean over S ----------
// Sum of {0,1} spike squares is order-exact -> reduction reorder is safe.
__global__ void epi_k(const float* __restrict__ spk2, float* __restrict__ out) {
    int b = blockIdx.x, d = threadIdx.x;  // 256 threads, d = output dim
    int p = d >> 7, e = d & 127;
    __shared__ float part[4];
    float acc = 0.f;
    for (int s = 0; s < 8; ++s) {
        float v = spk2[((size_t)p * 2048 + (size_t)(b * 8 + s)) * 128 + e];
        float sq = v;  // v in {0,1} -> v*v == v
#pragma unroll
        for (int off = 32; off > 0; off >>= 1) sq += __shfl_down(sq, off);
        if ((d & 63) == 0) part[d >> 6] = sq;
        __syncthreads();
        float nrm = sqrtf(part[0] + part[1] + part[2] + part[3]);
        acc += v / fmaxf(nrm, 1e-12f);
        __syncthreads();  // protect part[] before next s
    }
    out[(size_t)b * 256 + d] = acc * 0.125f;
}

extern "C" void kernel_launch(void* const* d_in, const int* in_sizes, int n_in,
                              void* d_out, int out_size, void* d_ws, size_t ws_size,
                              hipStream_t stream) {
    const float* a_seq = (const float*)d_in[0];
    const float* v_seq = (const float*)d_in[1];
    const float* W_a1  = (const float*)d_in[2];
    const float* b_a1  = (const float*)d_in[3];
    const float* W_a2  = (const float*)d_in[4];
    const float* b_a2  = (const float*)d_in[5];
    const float* W_v1  = (const float*)d_in[6];
    const float* b_v1  = (const float*)d_in[7];
    const float* W_v2  = (const float*)d_in[8];
    const float* b_v2  = (const float*)d_in[9];

    // workspace layout (needs ~161.4 MB)
    char* ws = (char*)d_ws;
    unsigned short* W1s  = (unsigned short*)(ws);              // 1,572,864 B
    unsigned short* W2s  = (unsigned short*)(ws + 1572864);    //   393,216 B
    unsigned short* spk1 = (unsigned short*)(ws + 1966080);    // 52,428,800 B
    float*          curb = (float*)(ws + 54394880);            // 104,857,600 B (cur1; reused as cur2)
    float*          spk2 = (float*)(ws + 159252480);           // 2,097,152 B
    float*          out  = (float*)d_out;

    prep_w<<<1280, 256, 0, stream>>>(W_a1, W_v1, W_a2, W_v2, W1s, W2s);

    // layer 1: cur1[p][51200][256]
    gemm_spl<512, 256, true><<<dim3(400, 2, 2), 256, 0, stream>>>(a_seq, v_seq, W1s, curb);
    lif1_k<<<dim3(2048, 2), 128, 0, stream>>>(curb, b_a1, b_v1, (unsigned int*)spk1);

    // layer 2: cur2[p][51200][128] (reuses curb)
    gemm_spl<256, 128, false><<<dim3(400, 1, 2), 256, 0, stream>>>(
        spk1, spk1 + (size_t)RBIG * 256, W2s, curb);
    lif2_k<<<dim3(2048, 2), 64, 0, stream>>>(curb, b_a2, b_v2, spk2);

    epi_k<<<256, 256, 0, stream>>>(spk2, out);
}